// Round 4
// baseline (207.944 us; speedup 1.0000x reference)
//
#include <hip/hip_runtime.h>
#include <hip/hip_bf16.h>

#define DNUM 64
#define LNUM 64
#define SNUM 10
#define QNUM 30
#define SPC  40
#define DIM  128
#define QPD  (LNUM*QNUM)    // 1920 queries per domain
#define SPD  (LNUM*SNUM)    // 640 supports per domain
#define WPD  (QPD/32)       // 60 query-groups per domain (32 queries/group)
#define NPAIRS (DNUM*WPD)   // 3840 query-groups; each handled by a PAIR of waves
#define NBLOCKS (NPAIRS/2)  // 1920 blocks
#define NSBLK  (DNUM*SPD/8) // 5120 norm_sup blocks
#define DSTRIDE 81920       // shorts per domain of sws (640 rows x 128)
#define TSTRIDE 2048        // shorts per dense 16-row tile (16 x 128)
#define LOG2E 1.44269504088896340736f

typedef __bf16 bf16x8 __attribute__((ext_vector_type(8)));
typedef float  f32x4  __attribute__((ext_vector_type(4)));
typedef unsigned int u32;
typedef unsigned short u16;

#if __has_builtin(__builtin_amdgcn_exp2f)
#define EXP2(x) __builtin_amdgcn_exp2f(x)
#else
#define EXP2(x) exp2f(x)
#endif

static __device__ __forceinline__ u32 f2bf(float x) {
    __bf16 h = (__bf16)x;
    return (u32)__builtin_bit_cast(u16, h);
}

// async global->LDS, 16B per lane; LDS dest = wave-uniform base + lane*16
static __device__ __forceinline__ void gload_lds16(const u16* g, u16* l) {
    __builtin_amdgcn_global_load_lds(
        (const __attribute__((address_space(1))) u32*)g,
        (__attribute__((address_space(3))) u32*)l, 16, 0, 0);
}

// ---------------- kernel 1: normalize supports (x log2e) -> DENSE tiles -----
// No pad rows: 8 classes (80 rows) pack exactly into 5 16-row MFMA tiles.
// Local row g in [0,80): tile t = g/16, A-row m = (g%4)*4 + ((g/4)%4).
// C-slot (tile, reg r) covers rows 4*(t*4+r)..+3 -> class is compile-time in
// the main kernel (4 mixed slots split at quad<2). Frag order within tile:
// k4*512 + (quadk*16 + m)*8 + half*4 (shorts) -> main kernel reads frag k4 as
// lane-contiguous 1 KB. Block id is XCD-chunk swizzled IDENTICALLY to the
// matching kernel so domain d's supports are written and read on the SAME
// XCD (per-XCD L2s are not cross-coherent; aligned placement makes the
// support stream L2-local instead of L3-latency).
__global__ __launch_bounds__(256)
void norm_sup(const float* __restrict__ emb, u16* __restrict__ sws)
{
    const int sb  = ((int)blockIdx.x & 7) * (NSBLK / 8) + ((int)blockIdx.x >> 3);
    const int hw  = sb * 8 + ((int)threadIdx.x >> 5);       // support row id
    const int sub = threadIdx.x & 31;
    const int d = hw / SPD, s = hw % SPD;
    const int cls = s / SNUM, rr = s % SNUM;
    const float4 v = *(const float4*)(emb + ((size_t)d * (LNUM * SPC) + cls * SPC + rr) * DIM + sub * 4);
    float ss = v.x*v.x + v.y*v.y + v.z*v.z + v.w*v.w;
    #pragma unroll
    for (int off = 16; off >= 1; off >>= 1) ss += __shfl_xor(ss, off);
    const float inv = LOG2E / (sqrtf(ss) + 1e-8f);
    uint2 pk;
    pk.x = f2bf(v.x*inv) | (f2bf(v.y*inv) << 16);
    pk.y = f2bf(v.z*inv) | (f2bf(v.w*inv) << 16);
    // dense placement
    const int G   = cls >> 3;                 // 8-class group
    const int g80 = (cls & 7) * SNUM + rr;    // row within group [0,80)
    const int T   = G * 5 + (g80 >> 4);       // domain tile [0,40)
    const int gt  = g80 & 15;
    const int m   = (gt & 3) * 4 + (gt >> 2); // A-row within tile
    const int k4 = sub >> 3, quadk = (sub >> 1) & 3, half = sub & 1;
    *(uint2*)(sws + (size_t)d * DSTRIDE + T * TSTRIDE + k4 * 512 + (quadk * 16 + m) * 8 + half * 4) = pk;
}

// ---------------- kernel 2: matching loss — LDS-staged pipeline -------------
// Round-3 diagnosis: ~900-1300 cy exposed per tile vs ~300 cy compute ->
// support loads are L3-latency and register prefetch can't hide them (the
// compiler's vmcnt drains the just-issued prefetch too). Fix: async
// global_load_lds staging, TRIPLE-buffered, counted s_waitcnt vmcnt(2) so 2
// stages stay in flight across barriers (T3/T4 minimal form). Waves sharing
// a half (w0/w2 tiles 0-19, w1/w3 tiles 20-39) read the staged tile via
// lane-contiguous ds_read_b128.
__global__ __launch_bounds__(256, 4)
void matching_kernel(const float* __restrict__ emb,
                     const u16* __restrict__ sws,
                     float2* __restrict__ partials,   // may be null -> atomic path
                     float* __restrict__ out)
{
    __shared__ __align__(16) u16 stg[3][2][TSTRIDE];  // 24 KB: [buf][half][tile]
    __shared__ float4 smx[4][32];                     // per-wave per-query state
    const int lane = threadIdx.x & 63;
    const int w    = threadIdx.x >> 6;                // wave in block: 0..3
    const int h    = w & 1;                           // class half: [h*32, +32)
    const int cq   = w >> 1;                          // stage chunk / pair id
    // XCD-chunked bijective swizzle (1920 % 8 == 0)
    const int sbid = ((int)blockIdx.x & 7) * (NBLOCKS / 8) + ((int)blockIdx.x >> 3);
    const int gp   = sbid * 2 + cq;                   // global query-group id
    const int d    = (sbid * 2) / WPD;                // both pairs share domain
    const int j0   = (gp % WPD) * 32;
    const int ml   = lane & 15;
    const int quad = lane >> 4;
    const bool qlo = (quad < 2);

    const u16* dsup = sws + (size_t)d * DSTRIDE;

    // stage tile T of this wave's half into stg[buf][h]: this wave covers
    // chunk cq (1 KB x 2 issues); sibling wave (other pair) covers the other.
    auto stage = [&](int buf, int T) {
        const u16* g = dsup + (size_t)(h * 20 + T) * TSTRIDE + cq * 1024 + lane * 8;
        u16* l = &stg[buf][h][cq * 1024];
        gload_lds16(g, l);
        gload_lds16(g + 512, l + 512);
    };

    // ---- queries: two 16-rows per lane, normalize in-register ----
    const float* ebase = emb + (size_t)d * (LNUM * SPC) * DIM;
    bf16x8 Bf[2][4];
    int ct[2];
    #pragma unroll
    for (int qt = 0; qt < 2; qt++) {
        const int qd = j0 + qt * 16 + ml;
        ct[qt] = qd / QNUM;                  // true class (labels are identity)
        const int row = ct[qt] * SPC + SNUM + (qd % QNUM);
        const float* qp = ebase + (size_t)row * DIM + quad * 8;
        float4 qv[4][2];
        #pragma unroll
        for (int k4 = 0; k4 < 4; k4++) {
            qv[k4][0] = *(const float4*)(qp + k4 * 32);
            qv[k4][1] = *(const float4*)(qp + k4 * 32 + 4);
        }
        float ss = 0.f;
        #pragma unroll
        for (int k4 = 0; k4 < 4; k4++) {
            float4 a = qv[k4][0], b = qv[k4][1];
            ss += a.x*a.x + a.y*a.y + a.z*a.z + a.w*a.w;
            ss += b.x*b.x + b.y*b.y + b.z*b.z + b.w*b.w;
        }
        ss += __shfl_xor(ss, 16);
        ss += __shfl_xor(ss, 32);
        const float inv = 1.0f / (sqrtf(ss) + 1e-8f);
        #pragma unroll
        for (int k4 = 0; k4 < 4; k4++) {
            float4 a = qv[k4][0], b = qv[k4][1];
            uint4 t;
            t.x = f2bf(a.x*inv) | (f2bf(a.y*inv) << 16);
            t.y = f2bf(a.z*inv) | (f2bf(a.w*inv) << 16);
            t.z = f2bf(b.x*inv) | (f2bf(b.y*inv) << 16);
            t.w = f2bf(b.z*inv) | (f2bf(b.w*inv) << 16);
            Bf[qt][k4] = __builtin_bit_cast(bf16x8, t);
        }
    }

    // ---- pipelined support stream: 20 dense tiles (= 32 classes) ----
    float tot[2] = {0.f, 0.f}, tv[2] = {0.f, 0.f}, mx[2] = {-1.f, -1.f};
    int   mi[2] = {0, 0};
    float ca[2][8] = {};                     // per-lane class masses (static idx)

    stage(0, 0);
    stage(1, 1);
    asm volatile("s_waitcnt vmcnt(2)" ::: "memory");   // tile 0 landed
    __syncthreads();

    #pragma unroll
    for (int T = 0; T < 20; T++) {
        const int buf = T % 3;
        if (T < 18) stage((T + 2) % 3, T + 2);         // keep 2 stages in flight

        const u16* lt = &stg[buf][h][0];
        bf16x8 Af[4];
        #pragma unroll
        for (int k4 = 0; k4 < 4; k4++)
            Af[k4] = *(const bf16x8*)(lt + k4 * 512 + lane * 8);  // ds_read_b128

        f32x4 acc[2] = {};
        #pragma unroll
        for (int k4 = 0; k4 < 4; k4++) {
            acc[0] = __builtin_amdgcn_mfma_f32_16x16x32_bf16(Af[k4], Bf[0][k4], acc[0], 0, 0, 0);
            acc[1] = __builtin_amdgcn_mfma_f32_16x16x32_bf16(Af[k4], Bf[1][k4], acc[1], 0, 0, 0);
        }

        // C: col=ml (query), row m=quad*4+r = support row 4*(t*4+r)+quad of
        // this 8-class group -> class of slot (t,r) is compile-time; mixed
        // slots (j=2,7,12,17) split exactly at quad<2.
        const int t = T % 5;
        #pragma unroll
        for (int r = 0; r < 4; r++) {
            const int j  = t * 4 + r;
            const int lc = (4 * j) / 10;
            const int hc = (4 * j + 3) / 10;
            #pragma unroll
            for (int q_ = 0; q_ < 2; q_++) {
                const float e = EXP2(acc[q_][r]);
                if (lc == hc) {
                    ca[q_][lc] += e;
                } else {
                    ca[q_][lc] += qlo ? e : 0.0f;
                    ca[q_][hc] += qlo ? 0.0f : e;
                }
            }
        }

        if (t == 4) {                        // finish an 8-class group
            const int cb = h * 32 + (T / 5) * 8;
            #pragma unroll
            for (int q_ = 0; q_ < 2; q_++) {
                #pragma unroll
                for (int c = 0; c < 8; c++) {
                    float m = ca[q_][c];
                    m += __shfl_xor(m, 16);
                    m += __shfl_xor(m, 32);
                    tot[q_] += m;
                    const bool better = m > mx[q_];   // first-max tie-break
                    mx[q_] = better ? m : mx[q_];
                    mi[q_] = better ? (cb + c) : mi[q_];
                    tv[q_] = ((cb + c) == ct[q_]) ? m : tv[q_];
                    ca[q_][c] = 0.0f;
                }
            }
        }

        if (T < 19) {                        // next tile must be resident
            if (T < 18) asm volatile("s_waitcnt vmcnt(2)" ::: "memory");
            else        asm volatile("s_waitcnt vmcnt(0)" ::: "memory");
            __syncthreads();
        }
    }

    // ---- publish per-wave half-state: slot (qt*16+ml) = query j0+lane ----
    if (lane < 32) {
        const bool q1 = (lane >= 16);        // qt of this slot == quad (0/1)
        const float t = q1 ? tot[1] : tot[0];
        const float v = q1 ? tv[1]  : tv[0];
        const float m = q1 ? mx[1]  : mx[0];
        const int   i = q1 ? mi[1]  : mi[0];
        smx[w][lane] = make_float4(t, v, m, __int_as_float(i));
    }
    __syncthreads();

    // ---- pair combine: even wave finishes all 32 queries of the pair ----
    if (h == 0) {
        float a = 0.f, b = 0.f;
        if (lane < 32) {
            const float4 A = smx[w][lane];       // classes [0,32)
            const float4 B = smx[w + 1][lane];   // classes [32,64)
            const float tt = A.x + B.x;          // exact: no pad mass
            const float vv = A.y + B.y;
            const int   ii = (B.z > A.z) ? __float_as_int(B.w) : __float_as_int(A.w);
            float p = vv / tt;
            p = fminf(fmaxf(p, 1e-8f), 1.0f);
            a = -__logf(p);
            const int c = (j0 + lane) / QNUM;
            b = (ii == c) ? 1.0f : 0.0f;
        }
        #pragma unroll
        for (int off = 1; off < 64; off <<= 1) {
            a += __shfl_xor(a, off);
            b += __shfl_xor(b, off);
        }
        if (partials) {
            if (lane == 0) partials[gp] = make_float2(a, b);
        } else if (lane == 0) {
            const float sc = 1.0f / (float)(DNUM * QPD);
            atomicAdd(out + 0, a * sc);
            atomicAdd(out + 1, b * sc);
        }
    }
}

// ---------------- kernel 3: reduce per-pair partials -> 2 outputs ----------
__global__ __launch_bounds__(256)
void reduce_partials(const float2* __restrict__ p, float* __restrict__ out)
{
    __shared__ float2 sm[4];
    float a = 0.f, b = 0.f;
    for (int i = threadIdx.x; i < NPAIRS; i += 256) {
        float2 v = p[i];
        a += v.x; b += v.y;
    }
    #pragma unroll
    for (int off = 1; off < 64; off <<= 1) {
        a += __shfl_xor(a, off);
        b += __shfl_xor(b, off);
    }
    const int w = threadIdx.x >> 6;
    if ((threadIdx.x & 63) == 0) sm[w] = make_float2(a, b);
    __syncthreads();
    if (threadIdx.x == 0) {
        float A = 0.f, B = 0.f;
        #pragma unroll
        for (int i = 0; i < 4; i++) { A += sm[i].x; B += sm[i].y; }
        const float sc = 1.0f / (float)(DNUM * QPD);
        out[0] = A * sc;
        out[1] = B * sc;
    }
}

extern "C" void kernel_launch(void* const* d_in, const int* in_sizes, int n_in,
                              void* d_out, int out_size, void* d_ws, size_t ws_size,
                              hipStream_t stream) {
    (void)in_sizes; (void)n_in; (void)out_size;
    const float* emb = (const float*)d_in[0];
    // d_in[1] (labels) unused: identity class mapping by construction.
    float* out = (float*)d_out;

    const size_t partBytes = (size_t)NPAIRS * sizeof(float2);      // 30720
    const size_t supBytes  = (size_t)DNUM * 40 * TSTRIDE * 2;      // 10.49 MB
    const bool usePart = ws_size >= partBytes + supBytes;

    float2* parts = usePart ? (float2*)d_ws : nullptr;
    u16* sws = (u16*)((char*)d_ws + (usePart ? partBytes : 0));

    if (!usePart) hipMemsetAsync(out, 0, 2 * sizeof(float), stream);
    norm_sup<<<NSBLK, 256, 0, stream>>>(emb, sws);
    matching_kernel<<<NBLOCKS, 256, 0, stream>>>(emb, sws, parts, out);
    if (usePart) reduce_partials<<<1, 256, 0, stream>>>(parts, out);
}

// Round 5
// 163.050 us; speedup vs baseline: 1.2753x; 1.2753x over previous
//
#include <hip/hip_runtime.h>
#include <hip/hip_bf16.h>

#define DNUM 64
#define LNUM 64
#define SNUM 10
#define QNUM 30
#define SPC  40
#define DIM  128
#define QPD  (LNUM*QNUM)    // 1920 queries per domain
#define NBLOCKS 1920        // 64 queries per block (4 waves x 16)
#define NSBLK  (DNUM*40)    // 2560 norm_sup blocks (one dense tile each)
#define DSTRIDE 81920       // shorts per domain of sws (40 tiles x 2048)
#define TSTRIDE 2048        // shorts per dense 16-row tile (16 x 128)
#define LOG2E 1.44269504088896340736f

typedef __bf16 bf16x8 __attribute__((ext_vector_type(8)));
typedef float  f32x4  __attribute__((ext_vector_type(4)));
typedef unsigned int u32;
typedef unsigned short u16;

#if __has_builtin(__builtin_amdgcn_exp2f)
#define EXP2(x) __builtin_amdgcn_exp2f(x)
#else
#define EXP2(x) exp2f(x)
#endif

static __device__ __forceinline__ u32 f2bf(float x) {
    __bf16 h = (__bf16)x;
    return (u32)__builtin_bit_cast(u16, h);
}

// async global->LDS, 16B per lane; LDS dest = wave-uniform base + lane*16
static __device__ __forceinline__ void gload_lds16(const u16* g, u16* l) {
    __builtin_amdgcn_global_load_lds(
        (const __attribute__((address_space(1))) u32*)g,
        (__attribute__((address_space(3))) u32*)l, 16, 0, 0);
}

// ---------------- kernel 1: normalize supports (x log2e) -> DENSE tiles -----
// One block per dense 16-row tile. Dense pack: 8 classes (80 rows) in 5
// tiles; source row g80 = t*16 + gt, A-row m = (gt&3)*4 + (gt>>2) -> C-slot
// (t, reg r) covers support rows 4*(t*4+r)..+3 (class compile-time in main
// kernel, mixed slots split at quad<2). Frag layout in tile: k-chunk ks
// (8 floats) at shorts k4*512 + (quadk*16+m)*8, k4=ks>>2, quadk=ks&3.
// Round-5 rewrite: old version stored scattered 8B at 256B stride; now
// transpose through LDS and store fully-coalesced 16B/lane. Block id is
// XCD-aligned with the matching kernel (domain d on XCD d>>3) so supports
// are written and read through the same XCD's L2.
__global__ __launch_bounds__(256)
void norm_sup(const float* __restrict__ emb, u16* __restrict__ sws)
{
    __shared__ __align__(16) u16 tile[TSTRIDE];       // 4 KB staging
    const int x  = (int)blockIdx.x & 7;               // XCD slot
    const int i  = (int)blockIdx.x >> 3;              // 0..319
    const int d  = x * 8 + i / 40;                    // domain (8 per XCD)
    const int T  = i % 40;                            // dense tile in domain
    const int G  = T / 5, tt = T % 5;
    const int t  = threadIdx.x;
    const int gt = t >> 4;                            // row within tile 0..15
    const int ks = t & 15;                            // 8-float k-chunk 0..15
    const int g80 = tt * 16 + gt;                     // row within 8-class group
    const int cls = G * 8 + g80 / SNUM;
    const int rr  = g80 % SNUM;
    const float* rp = emb + ((size_t)d * (LNUM * SPC) + cls * SPC + rr) * DIM + ks * 8;
    const float4 a = *(const float4*)rp;
    const float4 b = *(const float4*)(rp + 4);
    float ss = a.x*a.x + a.y*a.y + a.z*a.z + a.w*a.w
             + b.x*b.x + b.y*b.y + b.z*b.z + b.w*b.w;
    #pragma unroll
    for (int off = 8; off >= 1; off >>= 1) ss += __shfl_xor(ss, off);  // 16-group
    const float inv = LOG2E / (sqrtf(ss) + 1e-8f);
    uint4 pk;
    pk.x = f2bf(a.x*inv) | (f2bf(a.y*inv) << 16);
    pk.y = f2bf(a.z*inv) | (f2bf(a.w*inv) << 16);
    pk.z = f2bf(b.x*inv) | (f2bf(b.y*inv) << 16);
    pk.w = f2bf(b.z*inv) | (f2bf(b.w*inv) << 16);
    const int m  = (gt & 3) * 4 + (gt >> 2);
    const int k4 = ks >> 2, quadk = ks & 3;
    *(uint4*)&tile[k4 * 512 + (quadk * 16 + m) * 8] = pk;
    __syncthreads();
    const uint4* src = (const uint4*)tile;
    uint4* dst = (uint4*)(sws + (size_t)d * DSTRIDE + (size_t)T * TSTRIDE);
    dst[t]       = src[t];                            // 8 KB, fully coalesced
    dst[t + 256] = src[t + 256];
}

// ---------------- kernel 2: matching loss — shared-stream depth-5 pipeline --
// Round-4 lesson: (256,4) caps VGPR at ~64 on this toolchain (cap ~ 256/arg)
// and a fully-unrolled pipeline spills (115 MB scratch). This version keeps
// per-wave state tiny: each wave owns 16 queries over ALL 64 classes, all 4
// waves of the block share one support-tile stream staged in LDS (5 x 4 KB
// rotating buffers, period 5 == tiles per 8-class group -> static buffer
// index with a ROLLED group loop). Each wave stages 1 KB/tile -> steady
// s_waitcnt vmcnt(4) keeps a 5-tile-deep pipeline in flight.
__global__ __launch_bounds__(256, 2)
void matching_kernel(const float* __restrict__ emb,
                     const u16* __restrict__ sws,
                     float2* __restrict__ partials,   // may be null -> atomic path
                     float* __restrict__ out)
{
    __shared__ __align__(16) u16 stg[5][TSTRIDE];     // 20 KB rotating tiles
    __shared__ float2 sm2[4];
    const int lane = threadIdx.x & 63;
    const int w    = threadIdx.x >> 6;                // wave in block: 0..3
    // XCD-chunked bijective swizzle (1920 % 8 == 0): domain d lives on XCD d>>3
    const int sbid = ((int)blockIdx.x & 7) * (NBLOCKS / 8) + ((int)blockIdx.x >> 3);
    const int d    = sbid / 30;                       // 30 blocks per domain
    const int j0   = (sbid % 30) * 64;                // first query of block
    const int ml   = lane & 15;
    const int quad = lane >> 4;
    const bool qlo = (quad < 2);

    const u16* dsup = sws + (size_t)d * DSTRIDE;

    // ---- prologue: stage tiles 0..4 (1 KB chunk per wave per tile) ----
    #pragma unroll
    for (int p = 0; p < 5; ++p)
        gload_lds16(dsup + (size_t)p * TSTRIDE + w * 512 + lane * 8, &stg[p][w * 512]);
    const u16* gnext = dsup + 5 * TSTRIDE + w * 512 + lane * 8;

    // ---- queries: 16 rows for this wave, normalize in-register ----
    const int qd  = j0 + w * 16 + ml;
    const int ct  = qd / QNUM;                        // true class (identity labels)
    const int row = ct * SPC + SNUM + (qd % QNUM);
    const float* qp = emb + ((size_t)d * (LNUM * SPC) + row) * DIM + quad * 8;
    bf16x8 Bf[4];
    {
        float4 qv[4][2];
        #pragma unroll
        for (int k4 = 0; k4 < 4; k4++) {
            qv[k4][0] = *(const float4*)(qp + k4 * 32);
            qv[k4][1] = *(const float4*)(qp + k4 * 32 + 4);
        }
        float ss = 0.f;
        #pragma unroll
        for (int k4 = 0; k4 < 4; k4++) {
            float4 a = qv[k4][0], b = qv[k4][1];
            ss += a.x*a.x + a.y*a.y + a.z*a.z + a.w*a.w;
            ss += b.x*b.x + b.y*b.y + b.z*b.z + b.w*b.w;
        }
        ss += __shfl_xor(ss, 16);
        ss += __shfl_xor(ss, 32);
        const float inv = 1.0f / (sqrtf(ss) + 1e-8f);
        #pragma unroll
        for (int k4 = 0; k4 < 4; k4++) {
            float4 a = qv[k4][0], b = qv[k4][1];
            uint4 t;
            t.x = f2bf(a.x*inv) | (f2bf(a.y*inv) << 16);
            t.y = f2bf(a.z*inv) | (f2bf(a.w*inv) << 16);
            t.z = f2bf(b.x*inv) | (f2bf(b.y*inv) << 16);
            t.w = f2bf(b.z*inv) | (f2bf(b.w*inv) << 16);
            Bf[k4] = __builtin_bit_cast(bf16x8, t);
        }
    }

    float tot = 0.f, tv = 0.f, mx = -1.f;
    int   mi = 0;
    float ca[8] = {};                                 // class masses, static idx

    // tile body: vmcnt(VM) -> barrier (tile resident for all waves) ->
    // ds_read -> barrier (all waves done reading buf) -> restage buf -> MFMA
#define TILE(t_, VM_, STAGE_) do {                                            \
    asm volatile("s_waitcnt vmcnt(" #VM_ ")" ::: "memory");                   \
    __syncthreads();                                                          \
    bf16x8 Af[4];                                                             \
    _Pragma("unroll")                                                         \
    for (int k4 = 0; k4 < 4; ++k4)                                            \
        Af[k4] = *(const bf16x8*)(&stg[t_][0] + k4 * 512 + lane * 8);         \
    __syncthreads();                                                          \
    if (STAGE_) { gload_lds16(gnext, &stg[t_][w * 512]); gnext += TSTRIDE; }  \
    f32x4 acc = {};                                                           \
    _Pragma("unroll")                                                         \
    for (int k4 = 0; k4 < 4; ++k4)                                            \
        acc = __builtin_amdgcn_mfma_f32_16x16x32_bf16(Af[k4], Bf[k4], acc, 0, 0, 0); \
    _Pragma("unroll")                                                         \
    for (int r = 0; r < 4; ++r) {                                             \
        const int j  = (t_) * 4 + r;                                          \
        const int lc = (4 * j) / 10, hc = (4 * j + 3) / 10;                   \
        const float e = EXP2(acc[r]);                                         \
        if (lc == hc) ca[lc] += e;                                            \
        else { ca[lc] += qlo ? e : 0.0f; ca[hc] += qlo ? 0.0f : e; }          \
    }                                                                         \
} while (0)

#define FINISH(cb_) do {                                                      \
    _Pragma("unroll")                                                         \
    for (int c = 0; c < 8; ++c) {                                             \
        float m_ = ca[c];                                                     \
        m_ += __shfl_xor(m_, 16);                                             \
        m_ += __shfl_xor(m_, 32);                                             \
        tot += m_;                                                            \
        const bool better = m_ > mx;      /* first-max tie-break */           \
        mx = better ? m_ : mx;                                                \
        mi = better ? ((cb_) + c) : mi;                                       \
        tv = (((cb_) + c) == ct) ? m_ : tv;                                   \
        ca[c] = 0.0f;                                                         \
    }                                                                         \
} while (0)

    for (int Gx = 0; Gx < 7; ++Gx) {                  // rolled: keeps VGPR low
        TILE(0, 4, 1); TILE(1, 4, 1); TILE(2, 4, 1); TILE(3, 4, 1); TILE(4, 4, 1);
        FINISH(Gx * 8);
    }
    // peeled last group: no staging, descending vmcnt drains the pipeline
    TILE(0, 4, 0); TILE(1, 3, 0); TILE(2, 2, 0); TILE(3, 1, 0); TILE(4, 0, 0);
    FINISH(56);
#undef TILE
#undef FINISH

    // ---- epilogue: wave-local complete softmax state (16 queries) ----
    float p = tv / tot;                               // exact: no pad mass
    p = fminf(fmaxf(p, 1e-8f), 1.0f);
    const float nll = -__logf(p);
    const float cor = (mi == ct) ? 1.0f : 0.0f;
    float a = (quad == 0) ? nll : 0.0f;               // count each query once
    float b = (quad == 0) ? cor : 0.0f;
    #pragma unroll
    for (int off = 1; off < 64; off <<= 1) {
        a += __shfl_xor(a, off);
        b += __shfl_xor(b, off);
    }
    if (lane == 0) sm2[w] = make_float2(a, b);
    __syncthreads();
    if (threadIdx.x == 0) {
        float A = 0.f, B = 0.f;
        #pragma unroll
        for (int i2 = 0; i2 < 4; i2++) { A += sm2[i2].x; B += sm2[i2].y; }
        if (partials) {
            partials[sbid] = make_float2(A, B);
        } else {
            const float sc = 1.0f / (float)(DNUM * QPD);
            atomicAdd(out + 0, A * sc);
            atomicAdd(out + 1, B * sc);
        }
    }
}

// ---------------- kernel 3: reduce per-block partials -> 2 outputs ----------
__global__ __launch_bounds__(256)
void reduce_partials(const float2* __restrict__ p, float* __restrict__ out)
{
    __shared__ float2 sm[4];
    float a = 0.f, b = 0.f;
    for (int i = threadIdx.x; i < NBLOCKS; i += 256) {
        float2 v = p[i];
        a += v.x; b += v.y;
    }
    #pragma unroll
    for (int off = 1; off < 64; off <<= 1) {
        a += __shfl_xor(a, off);
        b += __shfl_xor(b, off);
    }
    const int w = threadIdx.x >> 6;
    if ((threadIdx.x & 63) == 0) sm[w] = make_float2(a, b);
    __syncthreads();
    if (threadIdx.x == 0) {
        float A = 0.f, B = 0.f;
        #pragma unroll
        for (int i = 0; i < 4; i++) { A += sm[i].x; B += sm[i].y; }
        const float sc = 1.0f / (float)(DNUM * QPD);
        out[0] = A * sc;
        out[1] = B * sc;
    }
}

extern "C" void kernel_launch(void* const* d_in, const int* in_sizes, int n_in,
                              void* d_out, int out_size, void* d_ws, size_t ws_size,
                              hipStream_t stream) {
    (void)in_sizes; (void)n_in; (void)out_size;
    const float* emb = (const float*)d_in[0];
    // d_in[1] (labels) unused: identity class mapping by construction.
    float* out = (float*)d_out;

    const size_t partBytes = (size_t)NBLOCKS * sizeof(float2);     // 15360
    const size_t supBytes  = (size_t)DNUM * 40 * TSTRIDE * 2;      // 10.49 MB
    const bool usePart = ws_size >= partBytes + supBytes;

    float2* parts = usePart ? (float2*)d_ws : nullptr;
    u16* sws = (u16*)((char*)d_ws + (usePart ? partBytes : 0));

    if (!usePart) hipMemsetAsync(out, 0, 2 * sizeof(float), stream);
    norm_sup<<<NSBLK, 256, 0, stream>>>(emb, sws);
    matching_kernel<<<NBLOCKS, 256, 0, stream>>>(emb, sws, parts, out);
    if (usePart) reduce_partials<<<1, 256, 0, stream>>>(parts, out);
}